// Round 1
// baseline (16986.411 us; speedup 1.0000x reference)
//
#include <hip/hip_runtime.h>

#define B_TOT 1024
#define T_LEN 512
#define D_INP 128
#define H 100
#define G4 400 /* 4*H */
#define BTILE 4
#define NTHR 256

__device__ __forceinline__ float fast_sigmoid(float z) {
    return 1.0f / (1.0f + __expf(-z));
}
__device__ __forceinline__ float fast_tanh(float z) {
    // tanh(z) = 1 - 2/(exp(2z)+1); exact at +-inf, ~1e-7 rel error
    return 1.0f - 2.0f / (__expf(2.0f * z) + 1.0f);
}

__global__ __launch_bounds__(NTHR) void lstm2_persistent(
    const float* __restrict__ x,
    const float* __restrict__ W_ih1, const float* __restrict__ W_hh1,
    const float* __restrict__ b_ih1, const float* __restrict__ b_hh1,
    const float* __restrict__ W_ih2, const float* __restrict__ W_hh2,
    const float* __restrict__ b_ih2, const float* __restrict__ b_hh2,
    float* __restrict__ out)
{
    __shared__ float s_x[BTILE][D_INP];
    __shared__ float s_h1[BTILE][H];
    __shared__ float s_c1[BTILE][H];
    __shared__ float s_h2[BTILE][H];
    __shared__ float s_c2[BTILE][H];
    __shared__ float s_g[BTILE][G4];
    __shared__ float s_b1[G4];
    __shared__ float s_b2[G4];

    const int tid = threadIdx.x;
    const int row0 = blockIdx.x * BTILE;

    // one-time init: fused biases, zero states
    for (int i = tid; i < G4; i += NTHR) {
        s_b1[i] = b_ih1[i] + b_hh1[i];
        s_b2[i] = b_ih2[i] + b_hh2[i];
    }
    for (int i = tid; i < BTILE * H; i += NTHR) {
        int r = i / H, j = i % H;
        s_h1[r][j] = 0.0f; s_c1[r][j] = 0.0f;
        s_h2[r][j] = 0.0f; s_c2[r][j] = 0.0f;
    }
    __syncthreads();

    for (int t = 0; t < T_LEN; ++t) {
        // ---- stage x_t for our 4 rows ----
        for (int i = tid; i < BTILE * D_INP; i += NTHR) {
            int r = i >> 7, d = i & 127;
            s_x[r][d] = x[((size_t)(row0 + r) * T_LEN + t) * D_INP + d];
        }
        __syncthreads();

        // ---- layer 1 gates: g-th output = x_t . W_ih1[g] + h1 . W_hh1[g] + b ----
        for (int g = tid; g < G4; g += NTHR) {
            float acc0, acc1, acc2, acc3;
            acc0 = acc1 = acc2 = acc3 = s_b1[g];
            const float4* wi = reinterpret_cast<const float4*>(W_ih1 + (size_t)g * D_INP);
            #pragma unroll 8
            for (int d4 = 0; d4 < D_INP / 4; ++d4) {
                float4 w = wi[d4];
                float4 v0 = *reinterpret_cast<const float4*>(&s_x[0][d4 * 4]);
                float4 v1 = *reinterpret_cast<const float4*>(&s_x[1][d4 * 4]);
                float4 v2 = *reinterpret_cast<const float4*>(&s_x[2][d4 * 4]);
                float4 v3 = *reinterpret_cast<const float4*>(&s_x[3][d4 * 4]);
                acc0 += w.x * v0.x + w.y * v0.y + w.z * v0.z + w.w * v0.w;
                acc1 += w.x * v1.x + w.y * v1.y + w.z * v1.z + w.w * v1.w;
                acc2 += w.x * v2.x + w.y * v2.y + w.z * v2.z + w.w * v2.w;
                acc3 += w.x * v3.x + w.y * v3.y + w.z * v3.z + w.w * v3.w;
            }
            const float4* wh = reinterpret_cast<const float4*>(W_hh1 + (size_t)g * H);
            #pragma unroll 5
            for (int k4 = 0; k4 < H / 4; ++k4) {
                float4 w = wh[k4];
                float4 v0 = *reinterpret_cast<const float4*>(&s_h1[0][k4 * 4]);
                float4 v1 = *reinterpret_cast<const float4*>(&s_h1[1][k4 * 4]);
                float4 v2 = *reinterpret_cast<const float4*>(&s_h1[2][k4 * 4]);
                float4 v3 = *reinterpret_cast<const float4*>(&s_h1[3][k4 * 4]);
                acc0 += w.x * v0.x + w.y * v0.y + w.z * v0.z + w.w * v0.w;
                acc1 += w.x * v1.x + w.y * v1.y + w.z * v1.z + w.w * v1.w;
                acc2 += w.x * v2.x + w.y * v2.y + w.z * v2.z + w.w * v2.w;
                acc3 += w.x * v3.x + w.y * v3.y + w.z * v3.z + w.w * v3.w;
            }
            s_g[0][g] = acc0; s_g[1][g] = acc1; s_g[2][g] = acc2; s_g[3][g] = acc3;
        }
        __syncthreads();

        // ---- layer 1 pointwise update ----
        for (int idx = tid; idx < BTILE * H; idx += NTHR) {
            int r = idx / H, j = idx % H;
            float ig = fast_sigmoid(s_g[r][j]);
            float fg = fast_sigmoid(s_g[r][H + j]);
            float gg = fast_tanh(s_g[r][2 * H + j]);
            float og = fast_sigmoid(s_g[r][3 * H + j]);
            float c = fg * s_c1[r][j] + ig * gg;
            s_c1[r][j] = c;
            s_h1[r][j] = og * fast_tanh(c);
        }
        __syncthreads();

        // ---- layer 2 gates: h1 . W_ih2[g] + h2 . W_hh2[g] + b ----
        for (int g = tid; g < G4; g += NTHR) {
            float acc0, acc1, acc2, acc3;
            acc0 = acc1 = acc2 = acc3 = s_b2[g];
            const float4* wi = reinterpret_cast<const float4*>(W_ih2 + (size_t)g * H);
            const float4* wh = reinterpret_cast<const float4*>(W_hh2 + (size_t)g * H);
            #pragma unroll 5
            for (int k4 = 0; k4 < H / 4; ++k4) {
                float4 w = wi[k4];
                float4 v0 = *reinterpret_cast<const float4*>(&s_h1[0][k4 * 4]);
                float4 v1 = *reinterpret_cast<const float4*>(&s_h1[1][k4 * 4]);
                float4 v2 = *reinterpret_cast<const float4*>(&s_h1[2][k4 * 4]);
                float4 v3 = *reinterpret_cast<const float4*>(&s_h1[3][k4 * 4]);
                acc0 += w.x * v0.x + w.y * v0.y + w.z * v0.z + w.w * v0.w;
                acc1 += w.x * v1.x + w.y * v1.y + w.z * v1.z + w.w * v1.w;
                acc2 += w.x * v2.x + w.y * v2.y + w.z * v2.z + w.w * v2.w;
                acc3 += w.x * v3.x + w.y * v3.y + w.z * v3.z + w.w * v3.w;
            }
            #pragma unroll 5
            for (int k4 = 0; k4 < H / 4; ++k4) {
                float4 w = wh[k4];
                float4 v0 = *reinterpret_cast<const float4*>(&s_h2[0][k4 * 4]);
                float4 v1 = *reinterpret_cast<const float4*>(&s_h2[1][k4 * 4]);
                float4 v2 = *reinterpret_cast<const float4*>(&s_h2[2][k4 * 4]);
                float4 v3 = *reinterpret_cast<const float4*>(&s_h2[3][k4 * 4]);
                acc0 += w.x * v0.x + w.y * v0.y + w.z * v0.z + w.w * v0.w;
                acc1 += w.x * v1.x + w.y * v1.y + w.z * v1.z + w.w * v1.w;
                acc2 += w.x * v2.x + w.y * v2.y + w.z * v2.z + w.w * v2.w;
                acc3 += w.x * v3.x + w.y * v3.y + w.z * v3.z + w.w * v3.w;
            }
            s_g[0][g] = acc0; s_g[1][g] = acc1; s_g[2][g] = acc2; s_g[3][g] = acc3;
        }
        __syncthreads();

        // ---- layer 2 pointwise update + output ----
        for (int idx = tid; idx < BTILE * H; idx += NTHR) {
            int r = idx / H, j = idx % H;
            float ig = fast_sigmoid(s_g[r][j]);
            float fg = fast_sigmoid(s_g[r][H + j]);
            float gg = fast_tanh(s_g[r][2 * H + j]);
            float og = fast_sigmoid(s_g[r][3 * H + j]);
            float c = fg * s_c2[r][j] + ig * gg;
            s_c2[r][j] = c;
            float hn = og * fast_tanh(c);
            s_h2[r][j] = hn;
            out[((size_t)(row0 + r) * T_LEN + t) * H + j] = hn;
        }
        __syncthreads();
    }
}

extern "C" void kernel_launch(void* const* d_in, const int* in_sizes, int n_in,
                              void* d_out, int out_size, void* d_ws, size_t ws_size,
                              hipStream_t stream) {
    const float* x     = (const float*)d_in[0];
    const float* W_ih1 = (const float*)d_in[1];
    const float* W_hh1 = (const float*)d_in[2];
    const float* b_ih1 = (const float*)d_in[3];
    const float* b_hh1 = (const float*)d_in[4];
    const float* W_ih2 = (const float*)d_in[5];
    const float* W_hh2 = (const float*)d_in[6];
    const float* b_ih2 = (const float*)d_in[7];
    const float* b_hh2 = (const float*)d_in[8];
    float* out = (float*)d_out;

    dim3 grid(B_TOT / BTILE);
    dim3 block(NTHR);
    lstm2_persistent<<<grid, block, 0, stream>>>(
        x, W_ih1, W_hh1, b_ih1, b_hh1, W_ih2, W_hh2, b_ih2, b_hh2, out);
}

// Round 2
// 8300.626 us; speedup vs baseline: 2.0464x; 2.0464x over previous
//
#include <hip/hip_runtime.h>
#include <hip/hip_bf16.h>

#define B_TOT 1024
#define T_LEN 512
#define D_INP 128
#define H 100
#define G4 400

__device__ __forceinline__ float fast_sigmoid(float z) {
    return 1.0f / (1.0f + __expf(-z));
}
__device__ __forceinline__ float fast_tanh(float z) {
    return 1.0f - 2.0f / (__expf(2.0f * z) + 1.0f);
}
__device__ __forceinline__ float bf_lo(unsigned u) { return __uint_as_float(u << 16); }
__device__ __forceinline__ float bf_hi(unsigned u) { return __uint_as_float(u & 0xffff0000u); }

__global__ void init_states(float* s, int n) {
    int i = blockIdx.x * 256 + threadIdx.x;
    if (i < n) s[i] = 0.f;
}

// ---------------- GEMM: X[rows][G4] = A[rows][K] @ W[G4][K]^T + (ba+bb) ----------------
// row rr maps to A + (rr/CT)*strideB + (rr%CT)*K   (handles both x-chunk and h1-chunk layouts)
template<int K, int CT>
__global__ __launch_bounds__(256) void gemm_xw(
    const float* __restrict__ A, long strideB,
    const float* __restrict__ W,
    const float* __restrict__ ba, const float* __restrict__ bb,
    float* __restrict__ X)
{
    constexpr int SK = K + 4;  // pad: bank-conflict-free column reads
    __shared__ __align__(16) float sA[128 * SK];
    __shared__ __align__(16) float sW[64 * SK];
    __shared__ float sBias[64];

    const int tid = threadIdx.x;
    const long row0 = (long)blockIdx.x * 128;
    const int g0 = blockIdx.y * 64;

    for (int m = tid; m < 128 * (K / 4); m += 256) {
        int r = m / (K / 4), kc = m % (K / 4);
        long rr = row0 + r;
        long off = (rr / CT) * strideB + (long)(rr % CT) * K + kc * 4;
        *reinterpret_cast<float4*>(&sA[r * SK + kc * 4]) =
            *reinterpret_cast<const float4*>(A + off);
    }
    for (int m = tid; m < 64 * (K / 4); m += 256) {
        int r = m / (K / 4), kc = m % (K / 4);
        int gg = g0 + r;
        float4 v = make_float4(0.f, 0.f, 0.f, 0.f);
        if (gg < G4) v = *reinterpret_cast<const float4*>(W + (long)gg * K + kc * 4);
        *reinterpret_cast<float4*>(&sW[r * SK + kc * 4]) = v;
    }
    if (tid < 64) {
        int gg = g0 + tid;
        sBias[tid] = (gg < G4) ? (ba[gg] + bb[gg]) : 0.f;
    }
    __syncthreads();

    const int tx = tid & 15, ty = tid >> 4;  // tx: gate quad, ty: row octet
    float acc[8][4];
    #pragma unroll
    for (int i = 0; i < 8; ++i)
        #pragma unroll
        for (int j = 0; j < 4; ++j) acc[i][j] = 0.f;

    #pragma unroll 4
    for (int k4 = 0; k4 < K / 4; ++k4) {
        float4 wv[4];
        #pragma unroll
        for (int j = 0; j < 4; ++j)
            wv[j] = *reinterpret_cast<const float4*>(&sW[(tx * 4 + j) * SK + k4 * 4]);
        #pragma unroll
        for (int i = 0; i < 8; ++i) {
            float4 av = *reinterpret_cast<const float4*>(&sA[(ty * 8 + i) * SK + k4 * 4]);
            #pragma unroll
            for (int j = 0; j < 4; ++j) {
                acc[i][j] += av.x * wv[j].x + av.y * wv[j].y + av.z * wv[j].z + av.w * wv[j].w;
            }
        }
    }

    if (g0 + tx * 4 + 4 <= G4) {
        float b0 = sBias[tx * 4 + 0], b1 = sBias[tx * 4 + 1];
        float b2 = sBias[tx * 4 + 2], b3 = sBias[tx * 4 + 3];
        #pragma unroll
        for (int i = 0; i < 8; ++i) {
            float4 o = make_float4(acc[i][0] + b0, acc[i][1] + b1, acc[i][2] + b2, acc[i][3] + b3);
            *reinterpret_cast<float4*>(X + (row0 + ty * 8 + i) * G4 + g0 + tx * 4) = o;
        }
    }
}

// ---------------- recurrent step: gates = X + h @ Whh^T ; pointwise update ----------------
// lane 4j+q owns gate q*100+j for 4 batch rows; Whh cached bf16 in LDS; h fp32 in LDS.
template<int CT, bool WRITE_H1>
__global__ __launch_bounds__(448) void lstm_recur(
    const float* __restrict__ X,      // [B*CT][G4] preactivations (bias included)
    const float* __restrict__ Whh,    // [G4][H]
    float* __restrict__ stateH, float* __restrict__ stateC,  // [B][H]
    float* __restrict__ hout,         // WRITE_H1: [B*CT][H]; else out [B][T][H]
    int t0)
{
    __shared__ __align__(16) unsigned short sW[G4][104];  // bf16, rows padded 100->104 (zeros)
    __shared__ __align__(16) float sH[4][104];            // padded, pad zeros

    const int tid = threadIdx.x;
    const int row0 = blockIdx.x * 4;
    const bool act = tid < 400;
    const int q = tid & 3, j = tid >> 2;          // gate type, column
    const int orow = tid / 100, ok = tid % 100;   // cooperative h-write mapping (act only)

    // stage Whh -> bf16 LDS (+ zero pad cols)
    for (int m = tid; m < G4 * H; m += 448) {
        __hip_bfloat16 hb = __float2bfloat16(Whh[m]);
        sW[m / H][m % H] = *reinterpret_cast<unsigned short*>(&hb);
    }
    for (int m = tid; m < G4 * 4; m += 448) sW[m >> 2][100 + (m & 3)] = 0;
    if (tid < 4 * 104) sH[tid / 104][tid % 104] = 0.f;
    __syncthreads();
    if (act) sH[orow][ok] = stateH[(row0 + orow) * H + ok];
    float c[4];
    #pragma unroll
    for (int r = 0; r < 4; ++r) c[r] = act ? stateC[(row0 + r) * H + j] : 0.f;
    __syncthreads();

    const unsigned short* wrow = &sW[act ? (q * 100 + j) : 0][0];
    const float* xp[4];
    #pragma unroll
    for (int r = 0; r < 4; ++r)
        xp[r] = X + ((long)(row0 + r) * CT) * G4 + (q * 100 + j);
    float* op;
    if (WRITE_H1) op = hout + ((long)(row0 + orow) * CT) * H + ok;
    else          op = hout + ((long)(row0 + orow) * T_LEN + t0) * H + ok;

    float xg[4];
    #pragma unroll
    for (int r = 0; r < 4; ++r) xg[r] = act ? xp[r][0] : 0.f;

    for (int tc = 0; tc < CT; ++tc) {
        // prefetch next step's preactivations (hides HBM latency under this step)
        float xn[4] = {0.f, 0.f, 0.f, 0.f};
        if (act && tc + 1 < CT) {
            #pragma unroll
            for (int r = 0; r < 4; ++r) xn[r] = xp[r][(long)(tc + 1) * G4];
        }

        float acc[4] = {xg[0], xg[1], xg[2], xg[3]};
        float hnew[4] = {0.f, 0.f, 0.f, 0.f};
        if (act) {
            #pragma unroll
            for (int k8 = 0; k8 < 13; ++k8) {
                uint4 wu = *reinterpret_cast<const uint4*>(wrow + k8 * 8);
                float w0 = bf_lo(wu.x), w1 = bf_hi(wu.x), w2 = bf_lo(wu.y), w3 = bf_hi(wu.y);
                float w4 = bf_lo(wu.z), w5 = bf_hi(wu.z), w6 = bf_lo(wu.w), w7 = bf_hi(wu.w);
                #pragma unroll
                for (int r = 0; r < 4; ++r) {
                    float4 hA = *reinterpret_cast<const float4*>(&sH[r][k8 * 8]);
                    float4 hB = *reinterpret_cast<const float4*>(&sH[r][k8 * 8 + 4]);
                    acc[r] += w0 * hA.x + w1 * hA.y + w2 * hA.z + w3 * hA.w
                            + w4 * hB.x + w5 * hB.y + w6 * hB.z + w7 * hB.w;
                }
            }
            #pragma unroll
            for (int r = 0; r < 4; ++r) {
                float v0 = acc[r];
                float v1 = __shfl_xor(v0, 1, 4);
                float v2 = __shfl_xor(v0, 2, 4);
                float v3 = __shfl_xor(v1, 2, 4);
                // gate p lives at xor-distance q^p: pick(m)=[v0,v1,v2,v3][m]
                bool m0 = (q & 1), m1 = (q & 2);
                float ig = m1 ? (m0 ? v3 : v2) : (m0 ? v1 : v0);  // pick(q)
                float fg = m1 ? (m0 ? v2 : v3) : (m0 ? v0 : v1);  // pick(q^1)
                float gg = m1 ? (m0 ? v1 : v0) : (m0 ? v3 : v2);  // pick(q^2)
                float og = m1 ? (m0 ? v0 : v1) : (m0 ? v2 : v3);  // pick(q^3)
                ig = fast_sigmoid(ig); fg = fast_sigmoid(fg);
                gg = fast_tanh(gg);    og = fast_sigmoid(og);
                float cn = fg * c[r] + ig * gg;
                c[r] = cn;
                hnew[r] = og * fast_tanh(cn);
            }
        }
        __syncthreads();  // all sH reads of this step done
        if (act && q == 0) {
            #pragma unroll
            for (int r = 0; r < 4; ++r) sH[r][j] = hnew[r];
        }
        __syncthreads();  // new h visible
        if (act) op[(long)tc * H] = sH[orow][ok];
        #pragma unroll
        for (int r = 0; r < 4; ++r) xg[r] = xn[r];
    }

    // persist states across chunks
    if (act) stateH[(row0 + orow) * H + ok] = sH[orow][ok];
    if (act && q == 0) {
        #pragma unroll
        for (int r = 0; r < 4; ++r) stateC[(row0 + r) * H + j] = c[r];
    }
}

// ---------------- round-1 fallback (used only if workspace is too small) ----------------
__global__ __launch_bounds__(256) void lstm2_persistent(
    const float* __restrict__ x,
    const float* __restrict__ W_ih1, const float* __restrict__ W_hh1,
    const float* __restrict__ b_ih1, const float* __restrict__ b_hh1,
    const float* __restrict__ W_ih2, const float* __restrict__ W_hh2,
    const float* __restrict__ b_ih2, const float* __restrict__ b_hh2,
    float* __restrict__ out)
{
    __shared__ float s_x[4][D_INP];
    __shared__ float s_h1[4][H], s_c1[4][H], s_h2[4][H], s_c2[4][H];
    __shared__ float s_g[4][G4];
    __shared__ float s_b1[G4], s_b2[G4];
    const int tid = threadIdx.x;
    const int row0 = blockIdx.x * 4;
    for (int i = tid; i < G4; i += 256) { s_b1[i] = b_ih1[i] + b_hh1[i]; s_b2[i] = b_ih2[i] + b_hh2[i]; }
    for (int i = tid; i < 4 * H; i += 256) { int r = i / H, jj = i % H;
        s_h1[r][jj] = 0.f; s_c1[r][jj] = 0.f; s_h2[r][jj] = 0.f; s_c2[r][jj] = 0.f; }
    __syncthreads();
    for (int t = 0; t < T_LEN; ++t) {
        for (int i = tid; i < 4 * D_INP; i += 256) { int r = i >> 7, d = i & 127;
            s_x[r][d] = x[((size_t)(row0 + r) * T_LEN + t) * D_INP + d]; }
        __syncthreads();
        for (int g = tid; g < G4; g += 256) {
            float a0, a1, a2, a3; a0 = a1 = a2 = a3 = s_b1[g];
            const float4* wi = reinterpret_cast<const float4*>(W_ih1 + (size_t)g * D_INP);
            for (int d4 = 0; d4 < D_INP / 4; ++d4) {
                float4 w = wi[d4];
                float4 v0 = *reinterpret_cast<const float4*>(&s_x[0][d4 * 4]);
                float4 v1 = *reinterpret_cast<const float4*>(&s_x[1][d4 * 4]);
                float4 v2 = *reinterpret_cast<const float4*>(&s_x[2][d4 * 4]);
                float4 v3 = *reinterpret_cast<const float4*>(&s_x[3][d4 * 4]);
                a0 += w.x*v0.x + w.y*v0.y + w.z*v0.z + w.w*v0.w;
                a1 += w.x*v1.x + w.y*v1.y + w.z*v1.z + w.w*v1.w;
                a2 += w.x*v2.x + w.y*v2.y + w.z*v2.z + w.w*v2.w;
                a3 += w.x*v3.x + w.y*v3.y + w.z*v3.z + w.w*v3.w;
            }
            const float4* wh = reinterpret_cast<const float4*>(W_hh1 + (size_t)g * H);
            for (int k4 = 0; k4 < H / 4; ++k4) {
                float4 w = wh[k4];
                float4 v0 = *reinterpret_cast<const float4*>(&s_h1[0][k4 * 4]);
                float4 v1 = *reinterpret_cast<const float4*>(&s_h1[1][k4 * 4]);
                float4 v2 = *reinterpret_cast<const float4*>(&s_h1[2][k4 * 4]);
                float4 v3 = *reinterpret_cast<const float4*>(&s_h1[3][k4 * 4]);
                a0 += w.x*v0.x + w.y*v0.y + w.z*v0.z + w.w*v0.w;
                a1 += w.x*v1.x + w.y*v1.y + w.z*v1.z + w.w*v1.w;
                a2 += w.x*v2.x + w.y*v2.y + w.z*v2.z + w.w*v2.w;
                a3 += w.x*v3.x + w.y*v3.y + w.z*v3.z + w.w*v3.w;
            }
            s_g[0][g] = a0; s_g[1][g] = a1; s_g[2][g] = a2; s_g[3][g] = a3;
        }
        __syncthreads();
        for (int idx = tid; idx < 4 * H; idx += 256) {
            int r = idx / H, jj = idx % H;
            float ig = fast_sigmoid(s_g[r][jj]);
            float fg = fast_sigmoid(s_g[r][H + jj]);
            float gg = fast_tanh(s_g[r][2 * H + jj]);
            float og = fast_sigmoid(s_g[r][3 * H + jj]);
            float cc = fg * s_c1[r][jj] + ig * gg;
            s_c1[r][jj] = cc; s_h1[r][jj] = og * fast_tanh(cc);
        }
        __syncthreads();
        for (int g = tid; g < G4; g += 256) {
            float a0, a1, a2, a3; a0 = a1 = a2 = a3 = s_b2[g];
            const float4* wi = reinterpret_cast<const float4*>(W_ih2 + (size_t)g * H);
            const float4* wh = reinterpret_cast<const float4*>(W_hh2 + (size_t)g * H);
            for (int k4 = 0; k4 < H / 4; ++k4) {
                float4 w = wi[k4];
                float4 v0 = *reinterpret_cast<const float4*>(&s_h1[0][k4 * 4]);
                float4 v1 = *reinterpret_cast<const float4*>(&s_h1[1][k4 * 4]);
                float4 v2 = *reinterpret_cast<const float4*>(&s_h1[2][k4 * 4]);
                float4 v3 = *reinterpret_cast<const float4*>(&s_h1[3][k4 * 4]);
                a0 += w.x*v0.x + w.y*v0.y + w.z*v0.z + w.w*v0.w;
                a1 += w.x*v1.x + w.y*v1.y + w.z*v1.z + w.w*v1.w;
                a2 += w.x*v2.x + w.y*v2.y + w.z*v2.z + w.w*v2.w;
                a3 += w.x*v3.x + w.y*v3.y + w.z*v3.z + w.w*v3.w;
            }
            for (int k4 = 0; k4 < H / 4; ++k4) {
                float4 w = wh[k4];
                float4 v0 = *reinterpret_cast<const float4*>(&s_h2[0][k4 * 4]);
                float4 v1 = *reinterpret_cast<const float4*>(&s_h2[1][k4 * 4]);
                float4 v2 = *reinterpret_cast<const float4*>(&s_h2[2][k4 * 4]);
                float4 v3 = *reinterpret_cast<const float4*>(&s_h2[3][k4 * 4]);
                a0 += w.x*v0.x + w.y*v0.y + w.z*v0.z + w.w*v0.w;
                a1 += w.x*v1.x + w.y*v1.y + w.z*v1.z + w.w*v1.w;
                a2 += w.x*v2.x + w.y*v2.y + w.z*v2.z + w.w*v2.w;
                a3 += w.x*v3.x + w.y*v3.y + w.z*v3.z + w.w*v3.w;
            }
            s_g[0][g] = a0; s_g[1][g] = a1; s_g[2][g] = a2; s_g[3][g] = a3;
        }
        __syncthreads();
        for (int idx = tid; idx < 4 * H; idx += 256) {
            int r = idx / H, jj = idx % H;
            float ig = fast_sigmoid(s_g[r][jj]);
            float fg = fast_sigmoid(s_g[r][H + jj]);
            float gg = fast_tanh(s_g[r][2 * H + jj]);
            float og = fast_sigmoid(s_g[r][3 * H + jj]);
            float cc = fg * s_c2[r][jj] + ig * gg;
            s_c2[r][jj] = cc;
            float hn = og * fast_tanh(cc);
            s_h2[r][jj] = hn;
            out[((size_t)(row0 + r) * T_LEN + t) * H + jj] = hn;
        }
        __syncthreads();
    }
}

// ---------------- host ----------------
template<int CT>
static void run_pipeline(const float* x,
                         const float* W_ih1, const float* W_hh1, const float* b_ih1, const float* b_hh1,
                         const float* W_ih2, const float* W_hh2, const float* b_ih2, const float* b_hh2,
                         float* out, float* Xws, float* h1ws,
                         float* h1s, float* c1s, float* h2s, float* c2s,
                         hipStream_t stream)
{
    const int nCh = T_LEN / CT;
    dim3 gB((unsigned)(B_TOT * CT / 128), 7);
    for (int c = 0; c < nCh; ++c) {
        int t0 = c * CT;
        gemm_xw<D_INP, CT><<<gB, 256, 0, stream>>>(
            x + (size_t)t0 * D_INP, (long)T_LEN * D_INP, W_ih1, b_ih1, b_hh1, Xws);
        lstm_recur<CT, true><<<B_TOT / 4, 448, 0, stream>>>(
            Xws, W_hh1, h1s, c1s, h1ws, t0);
        gemm_xw<H, CT><<<gB, 256, 0, stream>>>(
            h1ws, (long)CT * H, W_ih2, b_ih2, b_hh2, Xws);
        lstm_recur<CT, false><<<B_TOT / 4, 448, 0, stream>>>(
            Xws, W_hh2, h2s, c2s, out, t0);
    }
}

extern "C" void kernel_launch(void* const* d_in, const int* in_sizes, int n_in,
                              void* d_out, int out_size, void* d_ws, size_t ws_size,
                              hipStream_t stream) {
    const float* x     = (const float*)d_in[0];
    const float* W_ih1 = (const float*)d_in[1];
    const float* W_hh1 = (const float*)d_in[2];
    const float* b_ih1 = (const float*)d_in[3];
    const float* b_hh1 = (const float*)d_in[4];
    const float* W_ih2 = (const float*)d_in[5];
    const float* W_hh2 = (const float*)d_in[6];
    const float* b_ih2 = (const float*)d_in[7];
    const float* b_hh2 = (const float*)d_in[8];
    float* out = (float*)d_out;

    auto need = [](int CT) -> size_t {
        return ((size_t)B_TOT * CT * G4 + (size_t)B_TOT * CT * H + 4ull * B_TOT * H) * sizeof(float);
    };

    int CT = 0;
    if (ws_size >= need(128)) CT = 128;
    else if (ws_size >= need(32)) CT = 32;

    if (CT == 0) {  // workspace too small: safe fallback
        lstm2_persistent<<<B_TOT / 4, 256, 0, stream>>>(
            x, W_ih1, W_hh1, b_ih1, b_hh1, W_ih2, W_hh2, b_ih2, b_hh2, out);
        return;
    }

    float* Xws  = (float*)d_ws;
    float* h1ws = Xws + (size_t)B_TOT * CT * G4;
    float* st   = h1ws + (size_t)B_TOT * CT * H;
    float* h1s = st;
    float* c1s = st + (size_t)B_TOT * H;
    float* h2s = st + 2ull * B_TOT * H;
    float* c2s = st + 3ull * B_TOT * H;

    int nstate = 4 * B_TOT * H;
    init_states<<<(nstate + 255) / 256, 256, 0, stream>>>(st, nstate);

    if (CT == 128)
        run_pipeline<128>(x, W_ih1, W_hh1, b_ih1, b_hh1, W_ih2, W_hh2, b_ih2, b_hh2,
                          out, Xws, h1ws, h1s, c1s, h2s, c2s, stream);
    else
        run_pipeline<32>(x, W_ih1, W_hh1, b_ih1, b_hh1, W_ih2, W_hh2, b_ih2, b_hh2,
                         out, Xws, h1ws, h1s, c1s, h2s, c2s, stream);
}

// Round 3
// 3363.541 us; speedup vs baseline: 5.0502x; 2.4678x over previous
//
#include <hip/hip_runtime.h>
#include <hip/hip_bf16.h>

#define B_TOT 1024
#define T_LEN 512
#define D_INP 128
#define H 100
#define G4 400

typedef _Float16 half8 __attribute__((ext_vector_type(8)));
typedef _Float16 h2 __attribute__((ext_vector_type(2)));
typedef float f32x4 __attribute__((ext_vector_type(4)));

__device__ __forceinline__ float fast_sigmoid(float z) {
    return 1.0f / (1.0f + __expf(-z));
}
__device__ __forceinline__ float fast_tanh(float z) {
    return 1.0f - 2.0f / (__expf(2.0f * z) + 1.0f);
}

__device__ __forceinline__ float dot2(unsigned a, unsigned b, float c) {
#if __has_builtin(__builtin_amdgcn_fdot2)
    return __builtin_amdgcn_fdot2(__builtin_bit_cast(h2, a), __builtin_bit_cast(h2, b), c, false);
#else
    h2 ha = __builtin_bit_cast(h2, a), hb = __builtin_bit_cast(h2, b);
    return c + (float)ha.x * (float)hb.x + (float)ha.y * (float)hb.y;
#endif
}
__device__ __forceinline__ unsigned pack2(float x, float y) {
    h2 v; v.x = (_Float16)x; v.y = (_Float16)y;
    return __builtin_bit_cast(unsigned, v);
}

__global__ void init_states(float* s, int n) {
    int i = blockIdx.x * 256 + threadIdx.x;
    if (i < n) s[i] = 0.f;
}

// ---- prep: fragment-ordered f16 W_ih, padded f16 W_hh, fused bias ----
// wfrag[((nt*4+kt)*64+lane)*8+e] = Wih[nt*16+(lane&15)][kt*32+(lane>>4)*8+e] (0 if k>=K)
__global__ void prep_layer(const float* __restrict__ Wih, int K,
                           const float* __restrict__ Whh,
                           const float* __restrict__ bih, const float* __restrict__ bhh,
                           _Float16* __restrict__ wfrag, _Float16* __restrict__ whhf,
                           float* __restrict__ biasf)
{
    int i = blockIdx.x * 256 + threadIdx.x;
    if (i < 51200) {
        int e = i & 7, lane = (i >> 3) & 63, kt = (i >> 9) & 3, nt = i >> 11;
        int g = nt * 16 + (lane & 15);
        int k = kt * 32 + (lane >> 4) * 8 + e;
        wfrag[i] = (k < K) ? (_Float16)Wih[g * K + k] : (_Float16)0.f;
        return;
    }
    i -= 51200;
    if (i < 41600) {
        int g = i / 104, k = i % 104;
        whhf[i] = (k < 100) ? (_Float16)Whh[g * 100 + k] : (_Float16)0.f;
        return;
    }
    i -= 41600;
    if (i < 400) biasf[i] = bih[i] + bhh[i];
}

// ---- MFMA GEMM: X[rows][400] = A[rows][K] @ Wih^T + bias, f16 inputs, f32 out ----
template<int K, int CT>
__global__ __launch_bounds__(512) void gemm_mfma(
    const float* __restrict__ A, long strideB,
    const _Float16* __restrict__ Wfrag,
    const float* __restrict__ biasf,
    float* __restrict__ X)
{
    __shared__ __align__(16) unsigned char sA[256 * 256];  // 256 rows x 128 f16, swizzled
    __shared__ float sBias[G4];

    const int tid = threadIdx.x;
    const long row0 = (long)blockIdx.x * 256;

    // stage A -> f16 LDS with XOR swizzle (byte ^= (row&7)<<4)
    {
        const int r = tid >> 1, kh = (tid & 1) * 64;
        long rr = row0 + r;
        const float* src = A + (rr / CT) * strideB + (long)(rr % CT) * K;
        #pragma unroll
        for (int i = 0; i < 16; ++i) {
            int k = kh + i * 4;
            float4 v = make_float4(0.f, 0.f, 0.f, 0.f);
            if (k + 4 <= K) v = *reinterpret_cast<const float4*>(src + k);
            unsigned byteoff = (unsigned)r * 256u + (unsigned)k * 2u;
            byteoff ^= (unsigned)((r & 7) << 4);
            *reinterpret_cast<uint2*>(sA + byteoff) = make_uint2(pack2(v.x, v.y), pack2(v.z, v.w));
        }
    }
    for (int i = tid; i < G4; i += 512) sBias[i] = biasf[i];
    __syncthreads();

    const int wv = tid >> 6, lane = tid & 63;
    const int lrow = lane & 15, lk = (lane >> 4) * 8;

    // A fragments: 2 M-subtiles x 4 K-tiles per wave
    half8 aF[2][4];
    #pragma unroll
    for (int s = 0; s < 2; ++s)
        #pragma unroll
        for (int kt = 0; kt < 4; ++kt) {
            int rowL = wv * 32 + s * 16 + lrow;
            unsigned byteoff = (unsigned)rowL * 256u + (unsigned)(kt * 32 + lk) * 2u;
            byteoff ^= (unsigned)((rowL & 7) << 4);
            aF[s][kt] = *reinterpret_cast<const half8*>(sA + byteoff);
        }

    const long rb0 = row0 + wv * 32 + (lane >> 4) * 4;
    for (int nt = 0; nt < 25; ++nt) {
        half8 bF[4];
        const _Float16* bp = Wfrag + ((long)(nt * 4) * 64 + lane) * 8;
        #pragma unroll
        for (int kt = 0; kt < 4; ++kt)
            bF[kt] = *reinterpret_cast<const half8*>(bp + (long)kt * 64 * 8);

        f32x4 acc0 = {0.f, 0.f, 0.f, 0.f}, acc1 = {0.f, 0.f, 0.f, 0.f};
        #pragma unroll
        for (int kt = 0; kt < 4; ++kt) {
            acc0 = __builtin_amdgcn_mfma_f32_16x16x32_f16(aF[0][kt], bF[kt], acc0, 0, 0, 0);
            acc1 = __builtin_amdgcn_mfma_f32_16x16x32_f16(aF[1][kt], bF[kt], acc1, 0, 0, 0);
        }
        const int col = nt * 16 + lrow;
        const float bv = sBias[col];
        #pragma unroll
        for (int r = 0; r < 4; ++r) {
            X[(rb0 + r) * G4 + col]      = acc0[r] + bv;
            X[(rb0 + 16 + r) * G4 + col] = acc1[r] + bv;
        }
    }
}

// ---- recurrent: gates = X + h @ Whh^T ; pointwise. Whh f16 in REGS, h f16 in LDS ----
template<int CT, bool H1OUT>
__global__ __launch_bounds__(448) void lstm_recur_f16(
    const float* __restrict__ X,          // [B*CT][G4], bias included
    const _Float16* __restrict__ Whhf,    // [400][104] f16, zero-padded
    float* __restrict__ stateH, float* __restrict__ stateC,
    float* __restrict__ hout, int t0)
{
    __shared__ __align__(16) _Float16 sH[4][104];

    const int tid = threadIdx.x;
    const int row0 = blockIdx.x * 4;
    const bool act = tid < 400;
    const int q = tid & 3, j = tid >> 2;
    const int orow = tid / 100, ok = tid % 100;

    // gate weight row -> registers (once)
    uint4 wreg[13];
    {
        const uint4* wr = reinterpret_cast<const uint4*>(Whhf + (long)(act ? (q * 100 + j) : 0) * 104);
        #pragma unroll
        for (int i = 0; i < 13; ++i) wreg[i] = wr[i];
    }

    if (tid < 4 * 104) (&sH[0][0])[tid] = (_Float16)0.f;
    __syncthreads();
    if (act) sH[orow][ok] = (_Float16)stateH[(row0 + orow) * H + ok];
    float c[4];
    #pragma unroll
    for (int r = 0; r < 4; ++r) c[r] = act ? stateC[(row0 + r) * H + j] : 0.f;
    __syncthreads();

    const float* xp[4];
    #pragma unroll
    for (int r = 0; r < 4; ++r)
        xp[r] = X + ((long)(row0 + r) * CT) * G4 + (q * 100 + j);
    float* op;
    if (H1OUT) op = hout + ((long)(row0 + orow) * CT) * H + ok;
    else       op = hout + ((long)(row0 + orow) * T_LEN + t0) * H + ok;

    float xg[4];
    #pragma unroll
    for (int r = 0; r < 4; ++r) xg[r] = act ? xp[r][0] : 0.f;

    for (int tc = 0; tc < CT; ++tc) {
        float xn[4] = {0.f, 0.f, 0.f, 0.f};
        if (act && tc + 1 < CT) {
            #pragma unroll
            for (int r = 0; r < 4; ++r) xn[r] = xp[r][(long)(tc + 1) * G4];
        }

        float acc[4] = {xg[0], xg[1], xg[2], xg[3]};
        float hnew[4] = {0.f, 0.f, 0.f, 0.f};
        if (act) {
            #pragma unroll
            for (int k8 = 0; k8 < 13; ++k8) {
                uint4 w = wreg[k8];
                #pragma unroll
                for (int r = 0; r < 4; ++r) {
                    uint4 hv = *reinterpret_cast<const uint4*>(&sH[r][k8 * 8]);
                    float a = acc[r];
                    a = dot2(w.x, hv.x, a);
                    a = dot2(w.y, hv.y, a);
                    a = dot2(w.z, hv.z, a);
                    a = dot2(w.w, hv.w, a);
                    acc[r] = a;
                }
            }
            #pragma unroll
            for (int r = 0; r < 4; ++r) {
                float v0 = acc[r];
                float v1 = __shfl_xor(v0, 1, 4);
                float v2 = __shfl_xor(v0, 2, 4);
                float v3 = __shfl_xor(v1, 2, 4);
                bool m0 = (q & 1), m1 = (q & 2);
                float ig = m1 ? (m0 ? v3 : v2) : (m0 ? v1 : v0);
                float fg = m1 ? (m0 ? v2 : v3) : (m0 ? v0 : v1);
                float gg = m1 ? (m0 ? v1 : v0) : (m0 ? v3 : v2);
                float og = m1 ? (m0 ? v0 : v1) : (m0 ? v2 : v3);
                ig = fast_sigmoid(ig); fg = fast_sigmoid(fg);
                gg = fast_tanh(gg);    og = fast_sigmoid(og);
                float cn = fg * c[r] + ig * gg;
                c[r] = cn;
                hnew[r] = og * fast_tanh(cn);
            }
        }
        __syncthreads();
        if (act && q == 0) {
            #pragma unroll
            for (int r = 0; r < 4; ++r) sH[r][j] = (_Float16)hnew[r];
        }
        __syncthreads();
        if (act) op[(long)tc * H] = (float)sH[orow][ok];
        #pragma unroll
        for (int r = 0; r < 4; ++r) xg[r] = xn[r];
    }

    if (act) stateH[(row0 + orow) * H + ok] = (float)sH[orow][ok];
    if (act && q == 0) {
        #pragma unroll
        for (int r = 0; r < 4; ++r) stateC[(row0 + r) * H + j] = c[r];
    }
}

// ---------------- round-1 fallback (tiny workspace only) ----------------
__global__ __launch_bounds__(256) void lstm2_persistent(
    const float* __restrict__ x,
    const float* __restrict__ W_ih1, const float* __restrict__ W_hh1,
    const float* __restrict__ b_ih1, const float* __restrict__ b_hh1,
    const float* __restrict__ W_ih2, const float* __restrict__ W_hh2,
    const float* __restrict__ b_ih2, const float* __restrict__ b_hh2,
    float* __restrict__ out)
{
    __shared__ float s_x[4][D_INP];
    __shared__ float s_h1[4][H], s_c1[4][H], s_h2[4][H], s_c2[4][H];
    __shared__ float s_g[4][G4];
    __shared__ float s_b1[G4], s_b2[G4];
    const int tid = threadIdx.x;
    const int row0 = blockIdx.x * 4;
    for (int i = tid; i < G4; i += 256) { s_b1[i] = b_ih1[i] + b_hh1[i]; s_b2[i] = b_ih2[i] + b_hh2[i]; }
    for (int i = tid; i < 4 * H; i += 256) { int r = i / H, jj = i % H;
        s_h1[r][jj] = 0.f; s_c1[r][jj] = 0.f; s_h2[r][jj] = 0.f; s_c2[r][jj] = 0.f; }
    __syncthreads();
    for (int t = 0; t < T_LEN; ++t) {
        for (int i = tid; i < 4 * D_INP; i += 256) { int r = i >> 7, d = i & 127;
            s_x[r][d] = x[((size_t)(row0 + r) * T_LEN + t) * D_INP + d]; }
        __syncthreads();
        for (int g = tid; g < G4; g += 256) {
            float a0, a1, a2, a3; a0 = a1 = a2 = a3 = s_b1[g];
            const float4* wi = reinterpret_cast<const float4*>(W_ih1 + (size_t)g * D_INP);
            for (int d4 = 0; d4 < D_INP / 4; ++d4) {
                float4 w = wi[d4];
                float4 v0 = *reinterpret_cast<const float4*>(&s_x[0][d4 * 4]);
                float4 v1 = *reinterpret_cast<const float4*>(&s_x[1][d4 * 4]);
                float4 v2 = *reinterpret_cast<const float4*>(&s_x[2][d4 * 4]);
                float4 v3 = *reinterpret_cast<const float4*>(&s_x[3][d4 * 4]);
                a0 += w.x*v0.x + w.y*v0.y + w.z*v0.z + w.w*v0.w;
                a1 += w.x*v1.x + w.y*v1.y + w.z*v1.z + w.w*v1.w;
                a2 += w.x*v2.x + w.y*v2.y + w.z*v2.z + w.w*v2.w;
                a3 += w.x*v3.x + w.y*v3.y + w.z*v3.z + w.w*v3.w;
            }
            const float4* wh = reinterpret_cast<const float4*>(W_hh1 + (size_t)g * H);
            for (int k4 = 0; k4 < H / 4; ++k4) {
                float4 w = wh[k4];
                float4 v0 = *reinterpret_cast<const float4*>(&s_h1[0][k4 * 4]);
                float4 v1 = *reinterpret_cast<const float4*>(&s_h1[1][k4 * 4]);
                float4 v2 = *reinterpret_cast<const float4*>(&s_h1[2][k4 * 4]);
                float4 v3 = *reinterpret_cast<const float4*>(&s_h1[3][k4 * 4]);
                a0 += w.x*v0.x + w.y*v0.y + w.z*v0.z + w.w*v0.w;
                a1 += w.x*v1.x + w.y*v1.y + w.z*v1.z + w.w*v1.w;
                a2 += w.x*v2.x + w.y*v2.y + w.z*v2.z + w.w*v2.w;
                a3 += w.x*v3.x + w.y*v3.y + w.z*v3.z + w.w*v3.w;
            }
            s_g[0][g] = a0; s_g[1][g] = a1; s_g[2][g] = a2; s_g[3][g] = a3;
        }
        __syncthreads();
        for (int idx = tid; idx < 4 * H; idx += 256) {
            int r = idx / H, jj = idx % H;
            float ig = fast_sigmoid(s_g[r][jj]);
            float fg = fast_sigmoid(s_g[r][H + jj]);
            float gg = fast_tanh(s_g[r][2 * H + jj]);
            float og = fast_sigmoid(s_g[r][3 * H + jj]);
            float cc = fg * s_c1[r][jj] + ig * gg;
            s_c1[r][jj] = cc; s_h1[r][jj] = og * fast_tanh(cc);
        }
        __syncthreads();
        for (int g = tid; g < G4; g += 256) {
            float a0, a1, a2, a3; a0 = a1 = a2 = a3 = s_b2[g];
            const float4* wi = reinterpret_cast<const float4*>(W_ih2 + (size_t)g * H);
            const float4* wh = reinterpret_cast<const float4*>(W_hh2 + (size_t)g * H);
            for (int k4 = 0; k4 < H / 4; ++k4) {
                float4 w = wi[k4];
                float4 v0 = *reinterpret_cast<const float4*>(&s_h1[0][k4 * 4]);
                float4 v1 = *reinterpret_cast<const float4*>(&s_h1[1][k4 * 4]);
                float4 v2 = *reinterpret_cast<const float4*>(&s_h1[2][k4 * 4]);
                float4 v3 = *reinterpret_cast<const float4*>(&s_h1[3][k4 * 4]);
                a0 += w.x*v0.x + w.y*v0.y + w.z*v0.z + w.w*v0.w;
                a1 += w.x*v1.x + w.y*v1.y + w.z*v1.z + w.w*v1.w;
                a2 += w.x*v2.x + w.y*v2.y + w.z*v2.z + w.w*v2.w;
                a3 += w.x*v3.x + w.y*v3.y + w.z*v3.z + w.w*v3.w;
            }
            for (int k4 = 0; k4 < H / 4; ++k4) {
                float4 w = wh[k4];
                float4 v0 = *reinterpret_cast<const float4*>(&s_h2[0][k4 * 4]);
                float4 v1 = *reinterpret_cast<const float4*>(&s_h2[1][k4 * 4]);
                float4 v2 = *reinterpret_cast<const float4*>(&s_h2[2][k4 * 4]);
                float4 v3 = *reinterpret_cast<const float4*>(&s_h2[3][k4 * 4]);
                a0 += w.x*v0.x + w.y*v0.y + w.z*v0.z + w.w*v0.w;
                a1 += w.x*v1.x + w.y*v1.y + w.z*v1.z + w.w*v1.w;
                a2 += w.x*v2.x + w.y*v2.y + w.z*v2.z + w.w*v2.w;
                a3 += w.x*v3.x + w.y*v3.y + w.z*v3.z + w.w*v3.w;
            }
            s_g[0][g] = a0; s_g[1][g] = a1; s_g[2][g] = a2; s_g[3][g] = a3;
        }
        __syncthreads();
        for (int idx = tid; idx < 4 * H; idx += 256) {
            int r = idx / H, jj = idx % H;
            float ig = fast_sigmoid(s_g[r][jj]);
            float fg = fast_sigmoid(s_g[r][H + jj]);
            float gg = fast_tanh(s_g[r][2 * H + jj]);
            float og = fast_sigmoid(s_g[r][3 * H + jj]);
            float cc = fg * s_c2[r][jj] + ig * gg;
            s_c2[r][jj] = cc;
            float hn = og * fast_tanh(cc);
            s_h2[r][jj] = hn;
            out[((size_t)(row0 + r) * T_LEN + t) * H + jj] = hn;
        }
        __syncthreads();
    }
}

// ---------------- host ----------------
template<int CT>
static void run_pipeline(const float* x,
                         const float* W_ih1, const float* W_hh1, const float* b_ih1, const float* b_hh1,
                         const float* W_ih2, const float* W_hh2, const float* b_ih2, const float* b_hh2,
                         float* out, float* Xws, float* h1ws,
                         float* h1s, float* c1s, float* h2s, float* c2s,
                         _Float16* wfrag1, _Float16* wfrag2,
                         _Float16* whh1f, _Float16* whh2f,
                         float* bias1, float* bias2,
                         hipStream_t stream)
{
    const int nCh = T_LEN / CT;
    const int prepg = (51200 + 41600 + 400 + 255) / 256;
    prep_layer<<<prepg, 256, 0, stream>>>(W_ih1, 128, W_hh1, b_ih1, b_hh1, wfrag1, whh1f, bias1);
    prep_layer<<<prepg, 256, 0, stream>>>(W_ih2, 100, W_hh2, b_ih2, b_hh2, wfrag2, whh2f, bias2);

    dim3 gG((unsigned)(B_TOT * CT / 256));
    for (int c = 0; c < nCh; ++c) {
        int t0 = c * CT;
        gemm_mfma<D_INP, CT><<<gG, 512, 0, stream>>>(
            x + (size_t)t0 * D_INP, (long)T_LEN * D_INP, wfrag1, bias1, Xws);
        lstm_recur_f16<CT, true><<<B_TOT / 4, 448, 0, stream>>>(
            Xws, whh1f, h1s, c1s, h1ws, t0);
        gemm_mfma<H, CT><<<gG, 512, 0, stream>>>(
            h1ws, (long)CT * H, wfrag2, bias2, Xws);
        lstm_recur_f16<CT, false><<<B_TOT / 4, 448, 0, stream>>>(
            Xws, whh2f, h2s, c2s, out, t0);
    }
}

extern "C" void kernel_launch(void* const* d_in, const int* in_sizes, int n_in,
                              void* d_out, int out_size, void* d_ws, size_t ws_size,
                              hipStream_t stream) {
    const float* x     = (const float*)d_in[0];
    const float* W_ih1 = (const float*)d_in[1];
    const float* W_hh1 = (const float*)d_in[2];
    const float* b_ih1 = (const float*)d_in[3];
    const float* b_hh1 = (const float*)d_in[4];
    const float* W_ih2 = (const float*)d_in[5];
    const float* W_hh2 = (const float*)d_in[6];
    const float* b_ih2 = (const float*)d_in[7];
    const float* b_hh2 = (const float*)d_in[8];
    float* out = (float*)d_out;

    auto need = [](int CT) -> size_t {
        size_t f32elems = (size_t)B_TOT * CT * G4 + (size_t)B_TOT * CT * H + 4ull * B_TOT * H
                        + 2ull * G4;                       // X, h1, states, biases
        size_t f16elems = 2ull * 51200 + 2ull * 41600;     // wfrags, whh
        return f32elems * 4 + f16elems * 2;
    };

    int CT = 0;
    if (ws_size >= need(64)) CT = 64;
    else if (ws_size >= need(32)) CT = 32;
    else if (ws_size >= need(16)) CT = 16;

    if (CT == 0) {
        lstm2_persistent<<<B_TOT / 4, 256, 0, stream>>>(
            x, W_ih1, W_hh1, b_ih1, b_hh1, W_ih2, W_hh2, b_ih2, b_hh2, out);
        return;
    }

    float* Xws  = (float*)d_ws;
    float* h1ws = Xws + (size_t)B_TOT * CT * G4;
    float* st   = h1ws + (size_t)B_TOT * CT * H;
    float* h1s = st;
    float* c1s = st + (size_t)B_TOT * H;
    float* h2s = st + 2ull * B_TOT * H;
    float* c2s = st + 3ull * B_TOT * H;
    float* bias1 = st + 4ull * B_TOT * H;
    float* bias2 = bias1 + G4;
    _Float16* f16base = (_Float16*)(bias2 + G4);
    _Float16* wfrag1 = f16base;
    _Float16* wfrag2 = wfrag1 + 51200;
    _Float16* whh1f  = wfrag2 + 51200;
    _Float16* whh2f  = whh1f + 41600;

    int nstate = 4 * B_TOT * H;
    init_states<<<(nstate + 255) / 256, 256, 0, stream>>>(st, nstate);

    if (CT == 64)
        run_pipeline<64>(x, W_ih1, W_hh1, b_ih1, b_hh1, W_ih2, W_hh2, b_ih2, b_hh2,
                         out, Xws, h1ws, h1s, c1s, h2s, c2s,
                         wfrag1, wfrag2, whh1f, whh2f, bias1, bias2, stream);
    else if (CT == 32)
        run_pipeline<32>(x, W_ih1, W_hh1, b_ih1, b_hh1, W_ih2, W_hh2, b_ih2, b_hh2,
                         out, Xws, h1ws, h1s, c1s, h2s, c2s,
                         wfrag1, wfrag2, whh1f, whh2f, bias1, bias2, stream);
    else
        run_pipeline<16>(x, W_ih1, W_hh1, b_ih1, b_hh1, W_ih2, W_hh2, b_ih2, b_hh2,
                         out, Xws, h1ws, h1s, c1s, h2s, c2s,
                         wfrag1, wfrag2, whh1f, whh2f, bias1, bias2, stream);
}

// Round 4
// 2199.920 us; speedup vs baseline: 7.7214x; 1.5289x over previous
//
#include <hip/hip_runtime.h>
#include <hip/hip_bf16.h>

#define B_TOT 1024
#define T_LEN 512
#define D_INP 128
#define H 100
#define HP 112      /* padded hidden */
#define NP 448      /* padded gate dim = 4*HP, gate-interleaved */
#define NT_TILES 28 /* NP/16 */
#define FRAG_ELEMS 57344 /* 28*4*64*8 */

typedef _Float16 half8 __attribute__((ext_vector_type(8)));
typedef float f32x4 __attribute__((ext_vector_type(4)));

__device__ __forceinline__ float fast_sigmoid(float z) {
    return 1.0f / (1.0f + __expf(-z));
}
__device__ __forceinline__ float fast_tanh(float z) {
    return 1.0f - 2.0f / (__expf(2.0f * z) + 1.0f);
}
__device__ __forceinline__ unsigned pack2(float x, float y) {
    _Float16 a = (_Float16)x, b = (_Float16)y;
    unsigned short ua = __builtin_bit_cast(unsigned short, a);
    unsigned short ub = __builtin_bit_cast(unsigned short, b);
    return (unsigned)ua | ((unsigned)ub << 16);
}

__global__ void init_states(float* s, int n) {
    int i = blockIdx.x * 256 + threadIdx.x;
    if (i < n) s[i] = 0.f;
}

// ---- prep: gate-permuted f16 fragments for W_ih1/W_ih2/W_hh1/W_hh2 + permuted biases ----
// col' = jb*64 + g*16 + l  (jb=0..6, g=gate 0..3, l=0..15); orig gate row G = g*100+jb*16+l
// frag[((nt*4+kt)*64+lane)*8+e] = W[G][kt*32+(lane>>4)*8+e]  (B-operand layout, zero-padded)
__global__ void prep_frags(const float* __restrict__ Wih1, const float* __restrict__ Wih2,
                           const float* __restrict__ Whh1, const float* __restrict__ Whh2,
                           const float* __restrict__ bih1, const float* __restrict__ bhh1,
                           const float* __restrict__ bih2, const float* __restrict__ bhh2,
                           _Float16* __restrict__ frags, /* 4*FRAG_ELEMS: wfrag1,wfrag2,whhf1,whhf2 */
                           float* __restrict__ biases    /* 2*NP */)
{
    int i = blockIdx.x * 256 + threadIdx.x;
    if (i < 4 * FRAG_ELEMS) {
        int sec = i / FRAG_ELEMS, j = i % FRAG_ELEMS;
        int e = j & 7, lane = (j >> 3) & 63, kt = (j >> 9) & 3, nt = j >> 11;
        int l = lane & 15, jb = nt >> 2, g = nt & 3;
        int hcol = jb * 16 + l;
        int k = kt * 32 + (lane >> 4) * 8 + e;
        const float* W = (sec == 0) ? Wih1 : (sec == 1) ? Wih2 : (sec == 2) ? Whh1 : Whh2;
        int Kreal = (sec == 0) ? 128 : 100;
        float v = 0.f;
        if (hcol < 100 && k < Kreal) v = W[(g * 100 + hcol) * Kreal + k];
        frags[i] = (_Float16)v;
        return;
    }
    i -= 4 * FRAG_ELEMS;
    if (i < 2 * NP) {
        int layer = i / NP, cp = i % NP;
        int jb = cp >> 6, g = (cp >> 4) & 3, l = cp & 15;
        int hcol = jb * 16 + l;
        float v = 0.f;
        if (hcol < 100) {
            int G = g * 100 + hcol;
            v = layer ? (bih2[G] + bhh2[G]) : (bih1[G] + bhh1[G]);
        }
        biases[i] = v;
    }
}

// ---- MFMA GEMM: X[rows][NP] = A[rows][K] @ Wfrag^T + bias (permuted cols), f32 out ----
template<bool AF16, int CT>
__global__ __launch_bounds__(512) void gemm_mfma(
    const void* __restrict__ Ap, long strideB,
    const _Float16* __restrict__ Wfrag,
    const float* __restrict__ biasf,
    float* __restrict__ X)
{
    __shared__ __align__(16) unsigned char sA[256 * 256]; // 256 rows x 128 f16, XOR-swizzled
    __shared__ float sBias[NP];

    const int tid = threadIdx.x;
    const long row0 = (long)blockIdx.x * 256;

    // stage A -> f16 LDS, byte ^= (row&7)<<4
    {
        const int r = tid >> 1, kh = (tid & 1) * 64;
        long rr = row0 + r;
        if (!AF16) {
            const float* src = (const float*)Ap + (rr / CT) * strideB + (long)(rr % CT) * 128;
            #pragma unroll
            for (int i = 0; i < 16; ++i) {
                int k = kh + i * 4;
                float4 v = *reinterpret_cast<const float4*>(src + k);
                unsigned off = ((unsigned)r * 256u + (unsigned)k * 2u) ^ (unsigned)((r & 7) << 4);
                *reinterpret_cast<uint2*>(sA + off) = make_uint2(pack2(v.x, v.y), pack2(v.z, v.w));
            }
        } else {
            const _Float16* src = (const _Float16*)Ap + rr * HP;
            #pragma unroll
            for (int i = 0; i < 8; ++i) {
                int k = kh + i * 8;
                uint4 v = make_uint4(0u, 0u, 0u, 0u);
                if (k < HP) v = *reinterpret_cast<const uint4*>(src + k);
                unsigned off = ((unsigned)r * 256u + (unsigned)k * 2u) ^ (unsigned)((r & 7) << 4);
                *reinterpret_cast<uint4*>(sA + off) = v;
            }
        }
    }
    for (int i = tid; i < NP; i += 512) sBias[i] = biasf[i];
    __syncthreads();

    const int wv = tid >> 6, lane = tid & 63;
    const int lrow = lane & 15, lk = (lane >> 4) * 8;

    half8 aF[2][4];
    #pragma unroll
    for (int s = 0; s < 2; ++s)
        #pragma unroll
        for (int kt = 0; kt < 4; ++kt) {
            int rowL = wv * 32 + s * 16 + lrow;
            unsigned off = ((unsigned)rowL * 256u + (unsigned)(kt * 32 + lk) * 2u)
                         ^ (unsigned)((rowL & 7) << 4);
            aF[s][kt] = *reinterpret_cast<const half8*>(sA + off);
        }

    const long rb0 = row0 + wv * 32 + (lane >> 4) * 4;
    for (int nt = 0; nt < NT_TILES; ++nt) {
        half8 bF[4];
        const _Float16* bp = Wfrag + ((long)(nt * 4) * 64 + lane) * 8;
        #pragma unroll
        for (int kt = 0; kt < 4; ++kt)
            bF[kt] = *reinterpret_cast<const half8*>(bp + (long)kt * 512);

        f32x4 acc0 = {0.f, 0.f, 0.f, 0.f}, acc1 = {0.f, 0.f, 0.f, 0.f};
        #pragma unroll
        for (int kt = 0; kt < 4; ++kt) {
            acc0 = __builtin_amdgcn_mfma_f32_16x16x32_f16(aF[0][kt], bF[kt], acc0, 0, 0, 0);
            acc1 = __builtin_amdgcn_mfma_f32_16x16x32_f16(aF[1][kt], bF[kt], acc1, 0, 0, 0);
        }
        const int col = nt * 16 + lrow;
        const float bv = sBias[col];
        #pragma unroll
        for (int r = 0; r < 4; ++r) {
            X[(rb0 + r) * NP + col]      = acc0[r] + bv;
            X[(rb0 + 16 + r) * NP + col] = acc1[r] + bv;
        }
    }
}

// ---- MFMA recurrence: per step, gates = X + h @ Whh^T (one jb-quad per wave) ----
// block: 448 thr (7 waves), 16 batch rows. wave=jb; lane: l=lane&15 (h col within jb), rg=lane>>4.
// Lane owns (rows rg*4+0..3) x (col jb*16+l); holds i,f,g,o in its 4 accs -> no shuffles.
template<int CT, int MODE>  // MODE 0: write h1_seq f16 [B*CT][HP]; MODE 1: write out f32 [B][T][100]
__global__ __launch_bounds__(448, 2) void lstm_recur_mfma(
    const float* __restrict__ X,          // [B*CT][NP] permuted preactivations (bias incl.)
    const _Float16* __restrict__ whhf,    // B-fragments
    _Float16* __restrict__ hstate,        // [B][HP] f16
    float* __restrict__ cstate,           // [B][HP] f32
    void* __restrict__ hout, int t0)
{
    __shared__ __align__(16) unsigned char hbuf[16 * 256]; // 16 rows x 128 f16, XOR-swizzled

    const int tid = threadIdx.x;
    const int jb = tid >> 6, lane = tid & 63;
    const int l = lane & 15, rg = lane >> 4;
    const int b0 = blockIdx.x * 16;
    const int col = jb * 16 + l;

    // W_hh B-fragments -> registers (persist across all steps)
    half8 bf[4][4];
    #pragma unroll
    for (int g = 0; g < 4; ++g)
        #pragma unroll
        for (int kt = 0; kt < 4; ++kt)
            bf[g][kt] = *reinterpret_cast<const half8*>(
                whhf + (((long)(jb * 4 + g) * 4 + kt) * 64 + lane) * 8);

    // h-state -> LDS (16 rows x 112 real cols; cols 112..127 zero)
    if (tid < 32) {  // zero the pad octets (k=112..127) of all rows: 16 rows x 2 octets
        int row = tid >> 1, c8 = 112 + (tid & 1) * 8;
        unsigned off = ((unsigned)row * 256u + (unsigned)c8 * 2u) ^ (unsigned)((row & 7) << 4);
        *reinterpret_cast<uint4*>(hbuf + off) = make_uint4(0u, 0u, 0u, 0u);
    }
    if (tid < 224) {
        int row = tid / 14, c8 = (tid % 14) * 8;
        uint4 v = *reinterpret_cast<const uint4*>(hstate + (long)(b0 + row) * HP + c8);
        unsigned off = ((unsigned)row * 256u + (unsigned)c8 * 2u) ^ (unsigned)((row & 7) << 4);
        *reinterpret_cast<uint4*>(hbuf + off) = v;
    }

    // c-state -> registers
    float cst[4];
    #pragma unroll
    for (int r = 0; r < 4; ++r)
        cst[r] = cstate[(long)(b0 + rg * 4 + r) * HP + col];

    // X pointers + first-step prefetch
    const float* xpr[4];
    #pragma unroll
    for (int r = 0; r < 4; ++r)
        xpr[r] = X + ((long)(b0 + rg * 4 + r) * CT) * NP + jb * 64 + l;
    float xc[4][4];
    #pragma unroll
    for (int g = 0; g < 4; ++g)
        #pragma unroll
        for (int r = 0; r < 4; ++r) xc[g][r] = xpr[r][g * 16];

    __syncthreads();

    for (int tc = 0; tc < CT; ++tc) {
        // prefetch next step's preactivations (full step to cover latency)
        float xn[4][4] = {{0.f,0.f,0.f,0.f},{0.f,0.f,0.f,0.f},{0.f,0.f,0.f,0.f},{0.f,0.f,0.f,0.f}};
        if (tc + 1 < CT) {
            #pragma unroll
            for (int g = 0; g < 4; ++g)
                #pragma unroll
                for (int r = 0; r < 4; ++r) xn[g][r] = xpr[r][(long)(tc + 1) * NP + g * 16];
        }

        // A-fragments of current h (all waves read all 16 rows)
        half8 af[4];
        #pragma unroll
        for (int kt = 0; kt < 4; ++kt) {
            unsigned off = ((unsigned)l * 256u + (unsigned)(kt * 32 + rg * 8) * 2u)
                         ^ (unsigned)((l & 7) << 4);
            af[kt] = *reinterpret_cast<const half8*>(hbuf + off);
        }
        __syncthreads();  // B1: all old-h reads complete before any new-h write

        f32x4 acc[4];
        #pragma unroll
        for (int g = 0; g < 4; ++g)
            acc[g] = (f32x4){xc[g][0], xc[g][1], xc[g][2], xc[g][3]};
        #pragma unroll
        for (int kt = 0; kt < 4; ++kt)
            #pragma unroll
            for (int g = 0; g < 4; ++g)
                acc[g] = __builtin_amdgcn_mfma_f32_16x16x32_f16(af[kt], bf[g][kt], acc[g], 0, 0, 0);

        // pointwise: lane has i,f,g,o for 4 rows x 1 col
        #pragma unroll
        for (int r = 0; r < 4; ++r) {
            float ig = fast_sigmoid(acc[0][r]);
            float fg = fast_sigmoid(acc[1][r]);
            float gg = fast_tanh(acc[2][r]);
            float og = fast_sigmoid(acc[3][r]);
            float c = fg * cst[r] + ig * gg;
            cst[r] = c;
            float h = og * fast_tanh(c);
            _Float16 hf = (_Float16)h;
            int row = rg * 4 + r;
            unsigned off = ((unsigned)row * 256u + (unsigned)col * 2u) ^ (unsigned)((row & 7) << 4);
            *reinterpret_cast<_Float16*>(hbuf + off) = hf;
            if (MODE == 0) {
                ((_Float16*)hout)[((long)(b0 + row) * CT + tc) * HP + col] = hf;
            } else {
                if (col < H)
                    ((float*)hout)[((long)(b0 + row) * T_LEN + (t0 + tc)) * H + col] = h;
            }
        }
        __syncthreads();  // B2: publish new h
        #pragma unroll
        for (int g = 0; g < 4; ++g)
            #pragma unroll
            for (int r = 0; r < 4; ++r) xc[g][r] = xn[g][r];
    }

    // persist states
    #pragma unroll
    for (int r = 0; r < 4; ++r)
        cstate[(long)(b0 + rg * 4 + r) * HP + col] = cst[r];
    if (tid < 224) {
        int row = tid / 14, c8 = (tid % 14) * 8;
        unsigned off = ((unsigned)row * 256u + (unsigned)c8 * 2u) ^ (unsigned)((row & 7) << 4);
        *reinterpret_cast<uint4*>(hstate + (long)(b0 + row) * HP + c8) =
            *reinterpret_cast<const uint4*>(hbuf + off);
    }
}

// ---------------- fp32 fallback (tiny workspace only) ----------------
__global__ __launch_bounds__(256) void lstm2_persistent(
    const float* __restrict__ x,
    const float* __restrict__ W_ih1, const float* __restrict__ W_hh1,
    const float* __restrict__ b_ih1, const float* __restrict__ b_hh1,
    const float* __restrict__ W_ih2, const float* __restrict__ W_hh2,
    const float* __restrict__ b_ih2, const float* __restrict__ b_hh2,
    float* __restrict__ out)
{
    __shared__ float s_x[4][D_INP];
    __shared__ float s_h1[4][H], s_c1[4][H], s_h2[4][H], s_c2[4][H];
    __shared__ float s_g[4][400];
    __shared__ float s_b1[400], s_b2[400];
    const int tid = threadIdx.x;
    const int row0 = blockIdx.x * 4;
    for (int i = tid; i < 400; i += 256) { s_b1[i] = b_ih1[i] + b_hh1[i]; s_b2[i] = b_ih2[i] + b_hh2[i]; }
    for (int i = tid; i < 4 * H; i += 256) { int r = i / H, jj = i % H;
        s_h1[r][jj] = 0.f; s_c1[r][jj] = 0.f; s_h2[r][jj] = 0.f; s_c2[r][jj] = 0.f; }
    __syncthreads();
    for (int t = 0; t < T_LEN; ++t) {
        for (int i = tid; i < 4 * D_INP; i += 256) { int r = i >> 7, d = i & 127;
            s_x[r][d] = x[((size_t)(row0 + r) * T_LEN + t) * D_INP + d]; }
        __syncthreads();
        for (int g = tid; g < 400; g += 256) {
            float a0, a1, a2, a3; a0 = a1 = a2 = a3 = s_b1[g];
            const float4* wi = reinterpret_cast<const float4*>(W_ih1 + (size_t)g * D_INP);
            for (int d4 = 0; d4 < D_INP / 4; ++d4) {
                float4 w = wi[d4];
                float4 v0 = *reinterpret_cast<const float4*>(&s_x[0][d4 * 4]);
                float4 v1 = *reinterpret_cast<const float4*>(&s_x[1][d4 * 4]);
                float4 v2 = *reinterpret_cast<const float4*>(&s_x[2][d4 * 4]);
                float4 v3 = *reinterpret_cast<const float4*>(&s_x[3][d4 * 4]);
                a0 += w.x*v0.x + w.y*v0.y + w.z*v0.z + w.w*v0.w;
                a1 += w.x*v1.x + w.y*v1.y + w.z*v1.z + w.w*v1.w;
                a2 += w.x*v2.x + w.y*v2.y + w.z*v2.z + w.w*v2.w;
                a3 += w.x*v3.x + w.y*v3.y + w.z*v3.z + w.w*v3.w;
            }
            const float4* wh = reinterpret_cast<const float4*>(W_hh1 + (size_t)g * H);
            for (int k4 = 0; k4 < H / 4; ++k4) {
                float4 w = wh[k4];
                float4 v0 = *reinterpret_cast<const float4*>(&s_h1[0][k4 * 4]);
                float4 v1 = *reinterpret_cast<const float4*>(&s_h1[1][k4 * 4]);
                float4 v2 = *reinterpret_cast<const float4*>(&s_h1[2][k4 * 4]);
                float4 v3 = *reinterpret_cast<const float4*>(&s_h1[3][k4 * 4]);
                a0 += w.x*v0.x + w.y*v0.y + w.z*v0.z + w.w*v0.w;
                a1 += w.x*v1.x + w.y*v1.y + w.z*v1.z + w.w*v1.w;
                a2 += w.x*v2.x + w.y*v2.y + w.z*v2.z + w.w*v2.w;
                a3 += w.x*v3.x + w.y*v3.y + w.z*v3.z + w.w*v3.w;
            }
            s_g[0][g] = a0; s_g[1][g] = a1; s_g[2][g] = a2; s_g[3][g] = a3;
        }
        __syncthreads();
        for (int idx = tid; idx < 4 * H; idx += 256) {
            int r = idx / H, jj = idx % H;
            float ig = fast_sigmoid(s_g[r][jj]);
            float fg = fast_sigmoid(s_g[r][H + jj]);
            float gg = fast_tanh(s_g[r][2 * H + jj]);
            float og = fast_sigmoid(s_g[r][3 * H + jj]);
            float cc = fg * s_c1[r][jj] + ig * gg;
            s_c1[r][jj] = cc; s_h1[r][jj] = og * fast_tanh(cc);
        }
        __syncthreads();
        for (int g = tid; g < 400; g += 256) {
            float a0, a1, a2, a3; a0 = a1 = a2 = a3 = s_b2[g];
            const float4* wi = reinterpret_cast<const float4*>(W_ih2 + (size_t)g * H);
            const float4* wh = reinterpret_cast<const float4*>(W_hh2 + (size_t)g * H);
            for (int k4 = 0; k4 < H / 4; ++k4) {
                float4 w = wi[k4];
                float4 v0 = *reinterpret_cast<const float4*>(&s_h1[0][k4 * 4]);
                float4 v1 = *reinterpret_cast<const float4*>(&s_h1[1][k4 * 4]);
                float4 v2 = *reinterpret_cast<const float4*>(&s_h1[2][k4 * 4]);
                float4 v3 = *reinterpret_cast<const float4*>(&s_h1[3][k4 * 4]);
                a0 += w.x*v0.x + w.y*v0.y + w.z*v0.z + w.w*v0.w;
                a1 += w.x*v1.x + w.y*v1.y + w.z*v1.z + w.w*v1.w;
                a2 += w.x*v2.x + w.y*v2.y + w.z*v2.z + w.w*v2.w;
                a3 += w.x*v3.x + w.y*v3.y + w.z*v3.z + w.w*v3.w;
            }
            for (int k4 = 0; k4 < H / 4; ++k4) {
                float4 w = wh[k4];
                float4 v0 = *reinterpret_cast<const float4*>(&s_h2[0][k4 * 4]);
                float4 v1 = *reinterpret_cast<const float4*>(&s_h2[1][k4 * 4]);
                float4 v2 = *reinterpret_cast<const float4*>(&s_h2[2][k4 * 4]);
                float4 v3 = *reinterpret_cast<const float4*>(&s_h2[3][k4 * 4]);
                a0 += w.x*v0.x + w.y*v0.y + w.z*v0.z + w.w*v0.w;
                a1 += w.x*v1.x + w.y*v1.y + w.z*v1.z + w.w*v1.w;
                a2 += w.x*v2.x + w.y*v2.y + w.z*v2.z + w.w*v2.w;
                a3 += w.x*v3.x + w.y*v3.y + w.z*v3.z + w.w*v3.w;
            }
            s_g[0][g] = a0; s_g[1][g] = a1; s_g[2][g] = a2; s_g[3][g] = a3;
        }
        __syncthreads();
        for (int idx = tid; idx < 4 * H; idx += 256) {
            int r = idx / H, jj = idx % H;
            float ig = fast_sigmoid(s_g[r][jj]);
            float fg = fast_sigmoid(s_g[r][H + jj]);
            float gg = fast_tanh(s_g[r][2 * H + jj]);
            float og = fast_sigmoid(s_g[r][3 * H + jj]);
            float cc = fg * s_c2[r][jj] + ig * gg;
            s_c2[r][jj] = cc;
            float hn = og * fast_tanh(cc);
            s_h2[r][jj] = hn;
            out[((size_t)(row0 + r) * T_LEN + t) * H + jj] = hn;
        }
        __syncthreads();
    }
}

// ---------------- host ----------------
template<int CT>
static void run_pipeline(const float* x, float* out,
                         float* X, _Float16* h1seq,
                         float* c1s, float* c2s, _Float16* h1s, _Float16* h2s,
                         const _Float16* wfrag1, const _Float16* wfrag2,
                         const _Float16* whhf1, const _Float16* whhf2,
                         const float* bias1, const float* bias2,
                         hipStream_t stream)
{
    const int nCh = T_LEN / CT;
    dim3 gG((unsigned)(B_TOT * CT / 256));
    for (int c = 0; c < nCh; ++c) {
        int t0 = c * CT;
        gemm_mfma<false, CT><<<gG, 512, 0, stream>>>(
            x + (size_t)t0 * D_INP, (long)T_LEN * D_INP, wfrag1, bias1, X);
        lstm_recur_mfma<CT, 0><<<B_TOT / 16, 448, 0, stream>>>(
            X, whhf1, h1s, c1s, h1seq, t0);
        gemm_mfma<true, CT><<<gG, 512, 0, stream>>>(
            h1seq, 0L, wfrag2, bias2, X);
        lstm_recur_mfma<CT, 1><<<B_TOT / 16, 448, 0, stream>>>(
            X, whhf2, h2s, c2s, out, t0);
    }
}

extern "C" void kernel_launch(void* const* d_in, const int* in_sizes, int n_in,
                              void* d_out, int out_size, void* d_ws, size_t ws_size,
                              hipStream_t stream) {
    const float* x     = (const float*)d_in[0];
    const float* W_ih1 = (const float*)d_in[1];
    const float* W_hh1 = (const float*)d_in[2];
    const float* b_ih1 = (const float*)d_in[3];
    const float* b_hh1 = (const float*)d_in[4];
    const float* W_ih2 = (const float*)d_in[5];
    const float* W_hh2 = (const float*)d_in[6];
    const float* b_ih2 = (const float*)d_in[7];
    const float* b_hh2 = (const float*)d_in[8];
    float* out = (float*)d_out;

    // f32-word budget: X + h1seq(f16) + cstates + hstates(f16) + frags(f16) + biases
    auto need = [](int CT) -> size_t {
        size_t w = (size_t)B_TOT * CT * NP          // X
                 + (size_t)B_TOT * CT * HP / 2      // h1seq f16
                 + 2ull * B_TOT * HP                // c1,c2 f32
                 + B_TOT * HP                       // h1,h2 f16 (2 * HP/2 words each)
                 + 2ull * FRAG_ELEMS                // 4 frags f16
                 + 2ull * NP;                       // biases
        return w * 4;
    };

    int CT = 0;
    if (ws_size >= need(64)) CT = 64;
    else if (ws_size >= need(32)) CT = 32;
    else if (ws_size >= need(16)) CT = 16;

    if (CT == 0) {
        lstm2_persistent<<<B_TOT / 4, 256, 0, stream>>>(
            x, W_ih1, W_hh1, b_ih1, b_hh1, W_ih2, W_hh2, b_ih2, b_hh2, out);
        return;
    }

    float* p = (float*)d_ws;
    float* X = p;                 p += (size_t)B_TOT * CT * NP;
    _Float16* h1seq = (_Float16*)p; p += (size_t)B_TOT * CT * HP / 2;
    float* c1s = p;               p += (size_t)B_TOT * HP;
    float* c2s = p;               p += (size_t)B_TOT * HP;
    _Float16* h1s = (_Float16*)p; p += (size_t)B_TOT * HP / 2;
    _Float16* h2s = (_Float16*)p; p += (size_t)B_TOT * HP / 2;
    _Float16* frags = (_Float16*)p; p += 2ull * FRAG_ELEMS;
    float* biases = p;            p += 2ull * NP;

    const _Float16* wfrag1 = frags;
    const _Float16* wfrag2 = frags + FRAG_ELEMS;
    const _Float16* whhf1  = frags + 2ull * FRAG_ELEMS;
    const _Float16* whhf2  = frags + 3ull * FRAG_ELEMS;
    const float* bias1 = biases;
    const float* bias2 = biases + NP;

    // zero c-states (f32) + h-states (f16): 2*B*HP + B*HP f32-words
    int nzero = 3 * B_TOT * HP;
    init_states<<<(nzero + 255) / 256, 256, 0, stream>>>(c1s, nzero);

    int nprep = 4 * FRAG_ELEMS + 2 * NP;
    prep_frags<<<(nprep + 255) / 256, 256, 0, stream>>>(
        W_ih1, W_ih2, W_hh1, W_hh2, b_ih1, b_hh1, b_ih2, b_hh2,
        frags, biases);

    if (CT == 64)
        run_pipeline<64>(x, out, X, h1seq, c1s, c2s, h1s, h2s,
                         wfrag1, wfrag2, whhf1, whhf2, bias1, bias2, stream);
    else if (CT == 32)
        run_pipeline<32>(x, out, X, h1seq, c1s, c2s, h1s, h2s,
                         wfrag1, wfrag2, whhf1, whhf2, bias1, bias2, stream);
    else
        run_pipeline<16>(x, out, X, h1seq, c1s, c2s, h1s, h2s,
                         wfrag1, wfrag2, whhf1, whhf2, bias1, bias2, stream);
}